// Round 4
// baseline (519.953 us; speedup 1.0000x reference)
//
#include <hip/hip_runtime.h>
#include <hip/hip_cooperative_groups.h>
#include <stdint.h>

typedef short short8 __attribute__((ext_vector_type(8)));
typedef float floatx4 __attribute__((ext_vector_type(4)));
typedef float f32x2 __attribute__((ext_vector_type(2)));

#define BK 256   // nodes per bucket

static __device__ __forceinline__ float bflo(unsigned int u) {
    union { unsigned int i; float f; } v; v.i = u << 16; return v.f;
}
static __device__ __forceinline__ float bfhi(unsigned int u) {
    union { unsigned int i; float f; } v; v.i = u & 0xffff0000u; return v.f;
}
static __device__ __forceinline__ unsigned short f2bf(float f) {
    union { float f; unsigned int i; } v; v.f = f;
    unsigned int u = v.i;
    unsigned int r = u + 0x7fffu + ((u >> 16) & 1u);
    return (unsigned short)(r >> 16);
}
// unpack u32 (2 bf16) -> float2 {lo, hi}; feeds v_pk_add_f32
static __device__ __forceinline__ f32x2 unp2(unsigned int u) {
    union { unsigned int i; float f; } lo, hi;
    lo.i = u << 16; hi.i = u & 0xffff0000u;
    f32x2 r; r.x = lo.f; r.y = hi.f; return r;
}

// ---------------- device helpers shared by fused + legacy CSR build ----------------

static __device__ void wconv_body(int i, const float* W1, const float* W2, const float* Wf,
                                  unsigned short* wb1, unsigned short* wb2, unsigned short* wbf) {
    if (i < 16384) {
        int k = i >> 7, n = i & 127;
        wb1[n * 128 + k] = f2bf(W1[i]);
    } else if (i < 32768) {
        int j = i - 16384, k = j >> 7, n = j & 127;
        wb2[n * 128 + k] = f2bf(W2[j]);
    } else if (i < 40960) {
        int j = i - 32768, k = j >> 6, n = j & 63;
        wbf[n * 128 + k] = f2bf(Wf[j]);
    }
}

// ---------------- fused CSR build + W convert: ONE cooperative kernel ----------------
// Rationale (round-3 post-mortem): aggregate is at its random-gather pattern ceiling
// (~3.7 TB/s L2-miss side, insensitive to VALU/MLP changes). The unexplained budget
// is ~100+ us consistent with per-launch overhead x 11 launches. Phases below are
// byte-identical to the previous standalone kernels, separated by grid.sync().
// Grid = max(K,256) blocks x 256 thr, 16KB LDS -> trivially co-resident.

__global__ __launch_bounds__(256) void k_csr_fused(
    const int* __restrict__ src, const int* __restrict__ dst,
    const float* __restrict__ W1, const float* __restrict__ W2, const float* __restrict__ Wf,
    unsigned short* __restrict__ wb1, unsigned short* __restrict__ wb2,
    unsigned short* __restrict__ wbf,
    int* bucket_cnt, int* bucket_off, int* bucket_cur,
    int* __restrict__ row_start, float* __restrict__ dinv,
    unsigned int* __restrict__ tmp, int* __restrict__ csr,
    int E, int N, int K) {
    cooperative_groups::grid_group grid = cooperative_groups::this_grid();
    __shared__ int h[4][512];     // phase 1 & 3 per-wave hists (8KB)
    __shared__ int s[512];        // phase 2 scan + phase 4 scn/cur
    __shared__ int deg4[4][BK];   // phase 4 (aliases nothing; 4KB)
    int t = threadIdx.x, w = t >> 6;
    int G = gridDim.x;
    int g0 = blockIdx.x * 256 + t, gs = G * 256;

    // ---- phase 0: zero bucket_cnt + W pre-convert (wconv result not needed until GEMM) ----
    for (int i = g0; i < 512; i += gs) bucket_cnt[i] = 0;
    for (int i = g0; i < 40960; i += gs) wconv_body(i, W1, W2, Wf, wb1, wb2, wbf);
    grid.sync();

    // ---- phase 1: coarse histogram of dst>>8 (per-wave LDS hists) ----
    {
        for (int i = t; i < 4 * 512; i += 256) ((int*)h)[i] = 0;
        __syncthreads();
        int per = (E + G - 1) / G;
        int lo = blockIdx.x * per, hi = min(lo + per, E);
        for (int e = lo + t; e < hi; e += 256) {
            unsigned int d = (unsigned int)dst[e];
            if (d < (unsigned int)N) atomicAdd(&h[w][d >> 8], 1);
        }
        __syncthreads();
        for (int i = t; i < K; i += 256) {
            int c = h[0][i] + h[1][i] + h[2][i] + h[3][i];
            if (c) atomicAdd(&bucket_cnt[i], c);
        }
    }
    grid.sync();

    // ---- phase 2: exclusive scan of 512 bucket counts (block 0; 2 elems/thread) ----
    if (blockIdx.x == 0) {
        int e0 = bucket_cnt[2 * t], e1 = bucket_cnt[2 * t + 1];
        int p = e0 + e1;
        s[t] = p; __syncthreads();
        for (int off = 1; off < 256; off <<= 1) {
            int x = (t >= off) ? s[t - off] : 0;
            __syncthreads();
            s[t] += x;
            __syncthreads();
        }
        int incl = s[t];
        int excl = incl - p;
        bucket_off[2 * t] = excl;        bucket_cur[2 * t] = excl;
        bucket_off[2 * t + 1] = excl + e0; bucket_cur[2 * t + 1] = excl + e0;
        if (t == 255) { bucket_off[512] = incl; row_start[N] = incl; }
    }
    grid.sync();

    // ---- phase 3: bucket-sort edges into packed 4B entries (src<<8)|(dst&255) ----
    {
        for (int i = t; i < 4 * 512; i += 256) ((int*)h)[i] = 0;
        __syncthreads();
        int per = (E + G - 1) / G;
        int lo = blockIdx.x * per, hi = min(lo + per, E);
        for (int e = lo + t; e < hi; e += 256) {
            unsigned int d = (unsigned int)dst[e];
            if (d < (unsigned int)N) atomicAdd(&h[w][d >> 8], 1);
        }
        __syncthreads();
        for (int k = t; k < K; k += 256) {
            int c0 = h[0][k], c1 = h[1][k], c2 = h[2][k], c3 = h[3][k];
            int tot = c0 + c1 + c2 + c3;
            int base = tot ? atomicAdd(&bucket_cur[k], tot) : 0;
            h[0][k] = base; h[1][k] = base + c0; h[2][k] = base + c0 + c1;
            h[3][k] = base + c0 + c1 + c2;
        }
        __syncthreads();
        for (int e = lo + t; e < hi; e += 256) {
            unsigned int d = (unsigned int)dst[e];
            if (d < (unsigned int)N) {
                unsigned int sv = (unsigned int)src[e];
                if (sv >= (unsigned int)N) sv = 0;
                int p = atomicAdd(&h[w][d >> 8], 1);
                tmp[p] = (sv << 8) | (d & 255u);
            }
        }
    }
    grid.sync();

    // ---- phase 4: per-bucket degrees -> scan -> dst-sorted csr + dinv (block-stride) ----
    // Inter-iteration safety: first op re-zeroes deg4 (not touched by the trailing
    // scatter), then a __syncthreads gates everything else.
    int* scn = s;          // 256 ints used
    int* cur = s + 256;    // 256 ints used
    for (int b = blockIdx.x; b < K; b += G) {
        int lo = bucket_off[b], hi = bucket_off[b + 1];
        for (int i = t; i < 4 * BK; i += 256) ((int*)deg4)[i] = 0;
        __syncthreads();
        for (int e = lo + t; e < hi; e += 256) atomicAdd(&deg4[w][tmp[e] & 255u], 1);
        __syncthreads();
        int v = deg4[0][t] + deg4[1][t] + deg4[2][t] + deg4[3][t];
        scn[t] = v; __syncthreads();
        for (int off = 1; off < 256; off <<= 1) {
            int x = (t >= off) ? scn[t - off] : 0;
            __syncthreads();
            scn[t] += x;
            __syncthreads();
        }
        int rs = lo + scn[t] - v;
        cur[t] = rs;
        int node = b * BK + t;
        if (node < N) { row_start[node] = rs; dinv[node] = rsqrtf((float)(v + 1)); }
        __syncthreads();
        for (int e = lo + t; e < hi; e += 256) {
            unsigned int p = tmp[e];
            int pos = atomicAdd(&cur[p & 255u], 1);
            csr[pos] = (int)(p >> 8);
        }
    }
}

// ---------------- legacy standalone CSR kernels (fallback if coop launch rejected) ----------------

__global__ void k_zero_cnt(int* bucket_cnt, int K) {
    int i = blockIdx.x * 256 + threadIdx.x;
    if (i < K) bucket_cnt[i] = 0;
}

__global__ __launch_bounds__(256) void k_hist(const int* __restrict__ dst, int* bucket_cnt,
                                              int E, int N, int K) {
    __shared__ int h[4][512];
    int t = threadIdx.x, w = t >> 6;
    for (int i = t; i < 4 * 512; i += 256) ((int*)h)[i] = 0;
    __syncthreads();
    int per = (E + gridDim.x - 1) / gridDim.x;
    int lo = blockIdx.x * per, hi = min(lo + per, E);
    for (int e = lo + t; e < hi; e += 256) {
        unsigned int d = (unsigned int)dst[e];
        if (d < (unsigned int)N) atomicAdd(&h[w][d >> 8], 1);
    }
    __syncthreads();
    for (int i = t; i < K; i += 256) {
        int c = h[0][i] + h[1][i] + h[2][i] + h[3][i];
        if (c) atomicAdd(&bucket_cnt[i], c);
    }
}

__global__ void k_scanK(const int* __restrict__ bucket_cnt, int* bucket_off, int* bucket_cur,
                        int* row_start, int K, int N) {
    __shared__ int s[512];
    int t = threadIdx.x;
    int v = (t < K) ? bucket_cnt[t] : 0;
    s[t] = v; __syncthreads();
    for (int off = 1; off < 512; off <<= 1) {
        int x = (t >= off) ? s[t - off] : 0;
        __syncthreads();
        s[t] += x;
        __syncthreads();
    }
    if (t < K) { bucket_off[t] = s[t] - v; bucket_cur[t] = s[t] - v; }
    if (t == K - 1) { bucket_off[K] = s[t]; row_start[N] = s[t]; }
}

__global__ __launch_bounds__(256) void k_binscatter(const int* __restrict__ src,
                                                    const int* __restrict__ dst,
                                                    int* bucket_cur, unsigned int* __restrict__ tmp,
                                                    int E, int N, int K) {
    __shared__ int h[4][512];
    int t = threadIdx.x, w = t >> 6;
    for (int i = t; i < 4 * 512; i += 256) ((int*)h)[i] = 0;
    __syncthreads();
    int per = (E + gridDim.x - 1) / gridDim.x;
    int lo = blockIdx.x * per, hi = min(lo + per, E);
    for (int e = lo + t; e < hi; e += 256) {
        unsigned int d = (unsigned int)dst[e];
        if (d < (unsigned int)N) atomicAdd(&h[w][d >> 8], 1);
    }
    __syncthreads();
    for (int k = t; k < K; k += 256) {
        int c0 = h[0][k], c1 = h[1][k], c2 = h[2][k], c3 = h[3][k];
        int tot = c0 + c1 + c2 + c3;
        int base = tot ? atomicAdd(&bucket_cur[k], tot) : 0;
        h[0][k] = base; h[1][k] = base + c0; h[2][k] = base + c0 + c1;
        h[3][k] = base + c0 + c1 + c2;
    }
    __syncthreads();
    for (int e = lo + t; e < hi; e += 256) {
        unsigned int d = (unsigned int)dst[e];
        if (d < (unsigned int)N) {
            unsigned int sv = (unsigned int)src[e];
            if (sv >= (unsigned int)N) sv = 0;
            int p = atomicAdd(&h[w][d >> 8], 1);
            tmp[p] = (sv << 8) | (d & 255u);
        }
    }
}

__global__ __launch_bounds__(256) void k_fine(const unsigned int* __restrict__ tmp,
                                              const int* __restrict__ bucket_off,
                                              int* __restrict__ row_start, float* __restrict__ dinv,
                                              int* __restrict__ csr, int N) {
    __shared__ int deg4[4][BK];
    __shared__ int scn[BK];
    __shared__ int cur[BK];
    int b = blockIdx.x, t = threadIdx.x, w = t >> 6;
    int lo = bucket_off[b], hi = bucket_off[b + 1];
    for (int i = t; i < 4 * BK; i += 256) ((int*)deg4)[i] = 0;
    __syncthreads();
    for (int e = lo + t; e < hi; e += 256) atomicAdd(&deg4[w][tmp[e] & 255u], 1);
    __syncthreads();
    int v = deg4[0][t] + deg4[1][t] + deg4[2][t] + deg4[3][t];
    scn[t] = v; __syncthreads();
    for (int off = 1; off < 256; off <<= 1) {
        int x = (t >= off) ? scn[t - off] : 0;
        __syncthreads();
        scn[t] += x;
        __syncthreads();
    }
    int rs = lo + scn[t] - v;
    cur[t] = rs;
    int node = b * BK + t;
    if (node < N) { row_start[node] = rs; dinv[node] = rsqrtf((float)(v + 1)); }
    __syncthreads();
    for (int e = lo + t; e < hi; e += 256) {
        unsigned int p = tmp[e];
        int pos = atomicAdd(&cur[p & 255u], 1);
        csr[pos] = (int)(p >> 8);
    }
}

__global__ void k_wconv_all(const float* __restrict__ W1, const float* __restrict__ W2,
                            const float* __restrict__ Wf, unsigned short* __restrict__ wb1,
                            unsigned short* __restrict__ wb2, unsigned short* __restrict__ wbf) {
    int i = blockIdx.x * 256 + threadIdx.x;
    wconv_body(i, W1, W2, Wf, wb1, wb2, wbf);
}

// ---------------- GEMM: out[M,NOUT] = X[M,128] @ W[128,NOUT], K=128 ----------------
// Wbf bf16 pre-transposed [NOUT][128]. X fp32 row-major (XF32) or bf16 row-major.
// Out bf16 row-major or fp32 row-major (OUTF32). Persistent: W staged once per block.

template <int NOUT, bool SCALE, bool BIAS, bool XF32, bool OUTF32>
__global__ __launch_bounds__(256, 2) void k_gemm(
    const void* __restrict__ Xv, const unsigned short* __restrict__ Wbf,
    const float* __restrict__ bias, const float* __restrict__ dinv,
    void* __restrict__ outv, int M, int MB) {
    // Wl[n*136 + k]; stride 136 (272B ≡ 4 banks mod 32 -> 2-way conflict = free)
    __shared__ __align__(16) unsigned short Wl[NOUT * 136];
    int t = threadIdx.x;
    for (int c = t; c < NOUT * 16; c += 256) {
        short8 v = *(const short8*)(Wbf + (size_t)c * 8);
        *(short8*)(&Wl[(c >> 4) * 136 + (c & 15) * 8]) = v;
    }
    __syncthreads();

    int wave = t >> 6, lane = t & 63;
    int quad = lane >> 4, l16 = lane & 15;
    constexpr int NT = NOUT / 16;

    for (int mb = blockIdx.x; mb < MB; mb += gridDim.x) {
        int m0 = mb * 64 + wave * 16;
        int mr = m0 + l16;
        int mrc = mr < M ? mr : M - 1;

        floatx4 acc[NT];
#pragma unroll
        for (int i = 0; i < NT; i++) acc[i] = (floatx4){0.f, 0.f, 0.f, 0.f};

#pragma unroll
        for (int kc = 0; kc < 4; kc++) {
            short8 a;
            if (XF32) {
                const float* X = (const float*)Xv;
                const float* p = X + (size_t)mrc * 128 + kc * 32 + quad * 8;
                float4 xa = *(const float4*)p;
                float4 xb = *(const float4*)(p + 4);
                a[0] = (short)f2bf(xa.x); a[1] = (short)f2bf(xa.y);
                a[2] = (short)f2bf(xa.z); a[3] = (short)f2bf(xa.w);
                a[4] = (short)f2bf(xb.x); a[5] = (short)f2bf(xb.y);
                a[6] = (short)f2bf(xb.z); a[7] = (short)f2bf(xb.w);
            } else {
                const unsigned short* X = (const unsigned short*)Xv;
                a = *(const short8*)(X + (size_t)mrc * 128 + kc * 32 + quad * 8);
            }
#pragma unroll
            for (int nt = 0; nt < NT; nt++) {
                short8 b = *(const short8*)(&Wl[(nt * 16 + l16) * 136 + kc * 32 + quad * 8]);
                acc[nt] = __builtin_amdgcn_mfma_f32_16x16x32_bf16(a, b, acc[nt], 0, 0, 0);
            }
        }

        // C layout: col = l16, row (within 16) = quad*4 + i
#pragma unroll
        for (int i = 0; i < 4; i++) {
            int r = m0 + quad * 4 + i;
            if (r >= M) continue;
            float sc = SCALE ? dinv[r] : 1.0f;
#pragma unroll
            for (int nt = 0; nt < NT; nt++) {
                int n = nt * 16 + l16;
                float v = acc[nt][i] * sc;
                if (BIAS) v += bias[n];
                if (OUTF32) {
                    ((float*)outv)[(size_t)r * NOUT + n] = v;
                } else {
                    ((unsigned short*)outv)[(size_t)r * NOUT + n] = f2bf(v);
                }
            }
        }
    }
}

// ---------------- Aggregation: 2 nodes per wave (at pattern ceiling; unchanged) ----------------
// out[d] = relu(dinv[d]*(Hs[d] + sum_nbr Hs[src]) + b).
// Each 32-lane HALF of the wave owns one node; grp = edge-slot, c16 = channel chunk.
// shfl discipline: every shfl executes with sources inside the issuing half's
// 32 lanes, so per-half divergent trip counts never read inactive lanes.

__global__ __launch_bounds__(256, 8) void k_aggregate(
    const unsigned short* __restrict__ Hs, const int* __restrict__ csr,
    const int* __restrict__ row_start,
    const float* __restrict__ dinv, const float* __restrict__ bias,
    unsigned short* __restrict__ out, int N, int E) {
    int wave = threadIdx.x >> 6, lane = threadIdx.x & 63;
    int half = lane >> 5;           // which node of the pair
    int grp = (lane >> 4) & 1;      // edge-slot group within the node
    int c16 = lane & 15;            // channel chunk
    int l32 = lane & 31;            // slot-index space within the node
    int sbase = half << 5;          // shfl source base for this half
    int node = blockIdx.x * 8 + wave * 2 + half;
    int Nm1 = N - 1;
    int node_c = node < N ? node : Nm1;   // clamp: no per-half early return possible
    unsigned int cb2 = (unsigned int)c16 << 4;  // byte offset of the 16B chunk
    const char* Hb = (const char*)Hs;

    int start = row_start[node_c];
    int end = row_start[node_c + 1];
    if (start < 0) start = 0;
    if (end > E) end = E;
    int cnt = end - start;
    if (cnt < 0) cnt = 0;

    // self-loop row: independent load, issued early
    uint4 us = *(const uint4*)(Hb + (((size_t)node_c << 8) | cb2));

    // prefetch up to 32 neighbor indices per node in one coalesced load, clamp once
    int pre = cnt < 32 ? cnt : 32;
    int idxv = 0;
    if (l32 < pre) idxv = min(max(csr[start + l32], 0), Nm1);

    f32x2 a01 = {0.f, 0.f}, a23 = {0.f, 0.f}, a45 = {0.f, 0.f}, a67 = {0.f, 0.f};
#define ACC8(u) do { a01 += unp2((u).x); a23 += unp2((u).y); \
                     a45 += unp2((u).z); a67 += unp2((u).w); } while (0)

    int full2 = pre >> 1;
    int it = 0;
    for (; it + 4 <= full2; it += 4) {  // sources all within own half
        int p = it * 2 + grp;
        int i0 = __shfl(idxv, sbase + p);
        int i1 = __shfl(idxv, sbase + p + 2);
        int i2 = __shfl(idxv, sbase + p + 4);
        int i3 = __shfl(idxv, sbase + p + 6);
        uint4 u0 = *(const uint4*)(Hb + (((unsigned int)i0 << 8) | cb2));
        uint4 u1 = *(const uint4*)(Hb + (((unsigned int)i1 << 8) | cb2));
        uint4 u2 = *(const uint4*)(Hb + (((unsigned int)i2 << 8) | cb2));
        uint4 u3 = *(const uint4*)(Hb + (((unsigned int)i3 << 8) | cb2));
        ACC8(u0); ACC8(u1); ACC8(u2); ACC8(u3);
    }
    for (; it < full2; it++) {
        int i0 = __shfl(idxv, sbase + it * 2 + grp);
        uint4 u0 = *(const uint4*)(Hb + (((unsigned int)i0 << 8) | cb2));
        ACC8(u0);
    }
    // tail (odd pre): shfl outside the divergent branch, clamped source in own half
    int eT = full2 * 2 + grp;
    int iT = __shfl(idxv, sbase + (eT < pre ? eT : 0));
    if (eT < pre) {
        uint4 u0 = *(const uint4*)(Hb + (((unsigned int)iT << 8) | cb2));
        ACC8(u0);
    }
    // overflow (degree > 32, ~1e-5 of nodes): direct csr loads, no shfl
    for (int e = start + 32 + grp; e < end; e += 2) {
        int ii = min(max(csr[e], 0), Nm1);
        uint4 u = *(const uint4*)(Hb + (((unsigned int)ii << 8) | cb2));
        ACC8(u);
    }
#undef ACC8

    float a0 = a01.x, a1 = a01.y, a2 = a23.x, a3 = a23.y;
    float a4 = a45.x, a5 = a45.y, a6 = a67.x, a7 = a67.y;

    // reduce the 2 edge groups: lanes l <-> l^16 stay within the same half
    a0 += __shfl_xor(a0, 16); a1 += __shfl_xor(a1, 16); a2 += __shfl_xor(a2, 16);
    a3 += __shfl_xor(a3, 16); a4 += __shfl_xor(a4, 16); a5 += __shfl_xor(a5, 16);
    a6 += __shfl_xor(a6, 16); a7 += __shfl_xor(a7, 16);

    // self-loop + epilogue (both groups compute; grp 0 of each half stores)
    a0 += bflo(us.x); a1 += bfhi(us.x); a2 += bflo(us.y); a3 += bfhi(us.y);
    a4 += bflo(us.z); a5 += bfhi(us.z); a6 += bflo(us.w); a7 += bfhi(us.w);

    float di = dinv[node_c];
    float4 b0 = *(const float4*)(bias + c16 * 8);
    float4 b1 = *(const float4*)(bias + c16 * 8 + 4);
    float r0 = fmaxf(fmaf(di, a0, b0.x), 0.f);
    float r1 = fmaxf(fmaf(di, a1, b0.y), 0.f);
    float r2 = fmaxf(fmaf(di, a2, b0.z), 0.f);
    float r3 = fmaxf(fmaf(di, a3, b0.w), 0.f);
    float r4 = fmaxf(fmaf(di, a4, b1.x), 0.f);
    float r5 = fmaxf(fmaf(di, a5, b1.y), 0.f);
    float r6 = fmaxf(fmaf(di, a6, b1.z), 0.f);
    float r7 = fmaxf(fmaf(di, a7, b1.w), 0.f);
    if (grp == 0 && node < N) {
        uint4 o;
        o.x = (unsigned int)f2bf(r0) | ((unsigned int)f2bf(r1) << 16);
        o.y = (unsigned int)f2bf(r2) | ((unsigned int)f2bf(r3) << 16);
        o.z = (unsigned int)f2bf(r4) | ((unsigned int)f2bf(r5) << 16);
        o.w = (unsigned int)f2bf(r6) | ((unsigned int)f2bf(r7) << 16);
        *(uint4*)(out + (((size_t)node << 7) | (size_t)(c16 * 8))) = o;
    }
}

// ---------------- launch ----------------

extern "C" void kernel_launch(void* const* d_in, const int* in_sizes, int n_in,
                              void* d_out, int out_size, void* d_ws, size_t ws_size,
                              hipStream_t stream) {
    const float* x  = (const float*)d_in[0];
    const int* ei   = (const int*)d_in[1];
    const float* W1 = (const float*)d_in[2];
    const float* b1 = (const float*)d_in[3];
    const float* W2 = (const float*)d_in[4];
    const float* b2 = (const float*)d_in[5];
    const float* Wf = (const float*)d_in[6];
    const float* bf = (const float*)d_in[7];

    int N = in_sizes[0] / 128;
    int E = in_sizes[1] / 2;
    const int* src = ei;
    const int* dst = ei + E;
    int K = (N + BK - 1) / BK;
    if (N >= (1 << 24) || K > 512) return;  // packing/scan assumptions

    size_t need = 0;
    auto pad = [](size_t b) { return (b + 255) & ~(size_t)255; };
    size_t o_bcnt = need; need += pad(512 * 4);
    size_t o_boff = need; need += pad(513 * 4);
    size_t o_bcur = need; need += pad(512 * 4);
    size_t o_rs   = need; need += pad(((size_t)N + 1) * 4);
    size_t o_dinv = need; need += pad((size_t)N * 4);
    size_t o_wbf  = need; need += pad((16384 + 16384 + 8192) * 2);
    size_t o_csr  = need; need += pad((size_t)E * 4);
    size_t o_hs   = need; need += pad((size_t)N * 128 * 2);
    size_t o_a    = need; need += pad((size_t)N * 128 * 2);
    if (ws_size < need) return;
    if ((size_t)E * 4 > (size_t)N * 128 * 2) return;  // tmp must fit in A alias

    char* ws = (char*)d_ws;
    int* bucket_cnt = (int*)(ws + o_bcnt);
    int* bucket_off = (int*)(ws + o_boff);
    int* bucket_cur = (int*)(ws + o_bcur);
    int* row_start  = (int*)(ws + o_rs);
    float* dinv     = (float*)(ws + o_dinv);
    unsigned short* wb1 = (unsigned short*)(ws + o_wbf);
    unsigned short* wb2 = wb1 + 16384;
    unsigned short* wbf = wb2 + 16384;
    int* csr        = (int*)(ws + o_csr);
    unsigned short* Hs = (unsigned short*)(ws + o_hs);
    unsigned short* A  = (unsigned short*)(ws + o_a);
    unsigned int* tmp  = (unsigned int*)A;  // alias: tmp dead before A's first write

    // ---- CSR build + W convert: ONE cooperative kernel (was 6 launches) ----
    int G = K > 256 ? K : 256;
    {
        const int* srcp = src; const int* dstp = dst;
        const float *W1p = W1, *W2p = W2, *Wfp = Wf;
        unsigned short *wb1p = wb1, *wb2p = wb2, *wbfp = wbf;
        int Ev = E, Nv = N, Kv = K;
        void* args[] = {
            (void*)&srcp, (void*)&dstp,
            (void*)&W1p, (void*)&W2p, (void*)&Wfp,
            (void*)&wb1p, (void*)&wb2p, (void*)&wbfp,
            (void*)&bucket_cnt, (void*)&bucket_off, (void*)&bucket_cur,
            (void*)&row_start, (void*)&dinv,
            (void*)&tmp, (void*)&csr,
            (void*)&Ev, (void*)&Nv, (void*)&Kv};
        hipError_t ce = hipLaunchCooperativeKernel((const void*)k_csr_fused,
                                                   dim3(G), dim3(256), args, 0, stream);
        if (ce != hipSuccess) {
            // fallback: legacy 6-launch path (coop launch rejected, e.g. under capture)
            k_wconv_all<<<160, 256, 0, stream>>>(W1, W2, Wf, wb1, wb2, wbf);
            k_zero_cnt<<<2, 256, 0, stream>>>(bucket_cnt, 512);
            k_hist<<<256, 256, 0, stream>>>(dst, bucket_cnt, E, N, K);
            k_scanK<<<1, 512, 0, stream>>>(bucket_cnt, bucket_off, bucket_cur, row_start, K, N);
            k_binscatter<<<256, 256, 0, stream>>>(src, dst, bucket_cur, tmp, E, N, K);
            k_fine<<<K, 256, 0, stream>>>(tmp, bucket_off, row_start, dinv, csr, N);
        }
    }

    int MB = (N + 63) / 64;
    int GG = (MB + 1) / 2;  // persistent: 2 row-tiles per block

    k_gemm<128, true, false, true, false><<<GG, 256, 0, stream>>>(x, wb1, nullptr, dinv, Hs, N, MB);
    k_aggregate<<<(N + 7) / 8, 256, 0, stream>>>(Hs, csr, row_start, dinv, b1, A, N, E);
    k_gemm<128, true, false, false, false><<<GG, 256, 0, stream>>>(A, wb2, nullptr, dinv, Hs, N, MB);
    k_aggregate<<<(N + 7) / 8, 256, 0, stream>>>(Hs, csr, row_start, dinv, b2, A, N, E);
    k_gemm<64, false, true, false, true><<<GG, 256, 0, stream>>>(A, wbf, bf, nullptr, d_out, N, MB);
}

// Round 5
// 348.569 us; speedup vs baseline: 1.4917x; 1.4917x over previous
//
#include <hip/hip_runtime.h>
#include <stdint.h>

typedef short short8 __attribute__((ext_vector_type(8)));
typedef float floatx4 __attribute__((ext_vector_type(4)));
typedef float f32x2 __attribute__((ext_vector_type(2)));

#define BK 256   // nodes per bucket

static __device__ __forceinline__ float bflo(unsigned int u) {
    union { unsigned int i; float f; } v; v.i = u << 16; return v.f;
}
static __device__ __forceinline__ float bfhi(unsigned int u) {
    union { unsigned int i; float f; } v; v.i = u & 0xffff0000u; return v.f;
}
static __device__ __forceinline__ unsigned short f2bf(float f) {
    union { float f; unsigned int i; } v; v.f = f;
    unsigned int u = v.i;
    unsigned int r = u + 0x7fffu + ((u >> 16) & 1u);
    return (unsigned short)(r >> 16);
}
// unpack u32 (2 bf16) -> float2 {lo, hi}; feeds v_pk_add_f32
static __device__ __forceinline__ f32x2 unp2(unsigned int u) {
    union { unsigned int i; float f; } lo, hi;
    lo.i = u << 16; hi.i = u & 0xffff0000u;
    f32x2 r; r.x = lo.f; r.y = hi.f; return r;
}

// ---------------- CSR build: two-level counting sort, packed 4B entries ----------------
// NOTE (round-4 post-mortem): cooperative grid.sync() fusion of this chain cost
// ~50us PER SYNC on MI355X (cross-XCD L2 coherence flush) -> legacy multi-launch
// chain restored. Only zero_cnt is merged into wconv (kernel-boundary ordering).

// W pre-convert fp32 [K][Nc] -> bf16 transposed [Nc][K]; also zeroes bucket_cnt
// (runs before k_hist, so the zeroing is ordered by the launch boundary).
__global__ void k_wconv_all(const float* __restrict__ W1, const float* __restrict__ W2,
                            const float* __restrict__ Wf, unsigned short* __restrict__ wb1,
                            unsigned short* __restrict__ wb2, unsigned short* __restrict__ wbf,
                            int* __restrict__ bucket_cnt) {
    int i = blockIdx.x * 256 + threadIdx.x;
    if (i < 512) bucket_cnt[i] = 0;
    if (i < 16384) {
        int k = i >> 7, n = i & 127;
        wb1[n * 128 + k] = f2bf(W1[i]);
    } else if (i < 32768) {
        int j = i - 16384, k = j >> 7, n = j & 127;
        wb2[n * 128 + k] = f2bf(W2[j]);
    } else if (i < 40960) {
        int j = i - 32768, k = j >> 6, n = j & 63;
        wbf[n * 128 + k] = f2bf(Wf[j]);
    }
}

// coarse histogram of dst>>8; per-wave LDS hists cut same-address contention
__global__ __launch_bounds__(256) void k_hist(const int* __restrict__ dst, int* bucket_cnt,
                                              int E, int N, int K) {
    __shared__ int h[4][512];
    int t = threadIdx.x, w = t >> 6;
    for (int i = t; i < 4 * 512; i += 256) ((int*)h)[i] = 0;
    __syncthreads();
    int per = (E + gridDim.x - 1) / gridDim.x;
    int lo = blockIdx.x * per, hi = min(lo + per, E);
    for (int e = lo + t; e < hi; e += 256) {
        unsigned int d = (unsigned int)dst[e];
        if (d < (unsigned int)N) atomicAdd(&h[w][d >> 8], 1);
    }
    __syncthreads();
    for (int i = t; i < K; i += 256) {
        int c = h[0][i] + h[1][i] + h[2][i] + h[3][i];
        if (c) atomicAdd(&bucket_cnt[i], c);
    }
}

// single block: exclusive scan of K bucket counts (K <= 512); sentinel row_start[N]
__global__ void k_scanK(const int* __restrict__ bucket_cnt, int* bucket_off, int* bucket_cur,
                        int* row_start, int K, int N) {
    __shared__ int s[512];
    int t = threadIdx.x;
    int v = (t < K) ? bucket_cnt[t] : 0;
    s[t] = v; __syncthreads();
    for (int off = 1; off < 512; off <<= 1) {
        int x = (t >= off) ? s[t - off] : 0;
        __syncthreads();
        s[t] += x;
        __syncthreads();
    }
    if (t < K) { bucket_off[t] = s[t] - v; bucket_cur[t] = s[t] - v; }
    if (t == K - 1) { bucket_off[K] = s[t]; row_start[N] = s[t]; }
}

// bucket-sort edges into packed 4B entries (src<<8)|(dst&255); per-wave hists/cursors
__global__ __launch_bounds__(256) void k_binscatter(const int* __restrict__ src,
                                                    const int* __restrict__ dst,
                                                    int* bucket_cur, unsigned int* __restrict__ tmp,
                                                    int E, int N, int K) {
    __shared__ int h[4][512];
    int t = threadIdx.x, w = t >> 6;
    for (int i = t; i < 4 * 512; i += 256) ((int*)h)[i] = 0;
    __syncthreads();
    int per = (E + gridDim.x - 1) / gridDim.x;
    int lo = blockIdx.x * per, hi = min(lo + per, E);
    for (int e = lo + t; e < hi; e += 256) {
        unsigned int d = (unsigned int)dst[e];
        if (d < (unsigned int)N) atomicAdd(&h[w][d >> 8], 1);
    }
    __syncthreads();
    for (int k = t; k < K; k += 256) {
        int c0 = h[0][k], c1 = h[1][k], c2 = h[2][k], c3 = h[3][k];
        int tot = c0 + c1 + c2 + c3;
        int base = tot ? atomicAdd(&bucket_cur[k], tot) : 0;
        h[0][k] = base; h[1][k] = base + c0; h[2][k] = base + c0 + c1;
        h[3][k] = base + c0 + c1 + c2;
    }
    __syncthreads();
    for (int e = lo + t; e < hi; e += 256) {
        unsigned int d = (unsigned int)dst[e];
        if (d < (unsigned int)N) {
            unsigned int sv = (unsigned int)src[e];
            if (sv >= (unsigned int)N) sv = 0;
            int p = atomicAdd(&h[w][d >> 8], 1);
            tmp[p] = (sv << 8) | (d & 255u);
        }
    }
}

// one block per bucket: degrees (per-wave hists) -> scan -> dst-sorted csr + dinv
__global__ __launch_bounds__(256) void k_fine(const unsigned int* __restrict__ tmp,
                                              const int* __restrict__ bucket_off,
                                              int* __restrict__ row_start, float* __restrict__ dinv,
                                              int* __restrict__ csr, int N) {
    __shared__ int deg4[4][BK];
    __shared__ int scn[BK];
    __shared__ int cur[BK];
    int b = blockIdx.x, t = threadIdx.x, w = t >> 6;
    int lo = bucket_off[b], hi = bucket_off[b + 1];
    for (int i = t; i < 4 * BK; i += 256) ((int*)deg4)[i] = 0;
    __syncthreads();
    for (int e = lo + t; e < hi; e += 256) atomicAdd(&deg4[w][tmp[e] & 255u], 1);
    __syncthreads();
    int v = deg4[0][t] + deg4[1][t] + deg4[2][t] + deg4[3][t];
    scn[t] = v; __syncthreads();
    for (int off = 1; off < 256; off <<= 1) {
        int x = (t >= off) ? scn[t - off] : 0;
        __syncthreads();
        scn[t] += x;
        __syncthreads();
    }
    int rs = lo + scn[t] - v;
    cur[t] = rs;
    int node = b * BK + t;
    if (node < N) { row_start[node] = rs; dinv[node] = rsqrtf((float)(v + 1)); }
    __syncthreads();
    for (int e = lo + t; e < hi; e += 256) {
        unsigned int p = tmp[e];
        int pos = atomicAdd(&cur[p & 255u], 1);
        csr[pos] = (int)(p >> 8);
    }
}

// ---------------- GEMM: out[M,NOUT] = X[M,128] @ W[128,NOUT], K=128 ----------------
// Wbf bf16 pre-transposed [NOUT][128]. X fp32 row-major (XF32) or bf16 row-major.
// Out bf16 row-major or fp32 row-major (OUTF32). Persistent: W staged once per block.
// (Only the XF32 instantiation remains in use: layer-1 x @ W1.)

template <int NOUT, bool SCALE, bool BIAS, bool XF32, bool OUTF32>
__global__ __launch_bounds__(256, 2) void k_gemm(
    const void* __restrict__ Xv, const unsigned short* __restrict__ Wbf,
    const float* __restrict__ bias, const float* __restrict__ dinv,
    void* __restrict__ outv, int M, int MB) {
    // Wl[n*136 + k]; stride 136 (272B ≡ 4 banks mod 32 -> 2-way conflict = free)
    __shared__ __align__(16) unsigned short Wl[NOUT * 136];
    int t = threadIdx.x;
    for (int c = t; c < NOUT * 16; c += 256) {
        short8 v = *(const short8*)(Wbf + (size_t)c * 8);
        *(short8*)(&Wl[(c >> 4) * 136 + (c & 15) * 8]) = v;
    }
    __syncthreads();

    int wave = t >> 6, lane = t & 63;
    int quad = lane >> 4, l16 = lane & 15;
    constexpr int NT = NOUT / 16;

    for (int mb = blockIdx.x; mb < MB; mb += gridDim.x) {
        int m0 = mb * 64 + wave * 16;
        int mr = m0 + l16;
        int mrc = mr < M ? mr : M - 1;

        floatx4 acc[NT];
#pragma unroll
        for (int i = 0; i < NT; i++) acc[i] = (floatx4){0.f, 0.f, 0.f, 0.f};

#pragma unroll
        for (int kc = 0; kc < 4; kc++) {
            short8 a;
            if (XF32) {
                const float* X = (const float*)Xv;
                const float* p = X + (size_t)mrc * 128 + kc * 32 + quad * 8;
                float4 xa = *(const float4*)p;
                float4 xb = *(const float4*)(p + 4);
                a[0] = (short)f2bf(xa.x); a[1] = (short)f2bf(xa.y);
                a[2] = (short)f2bf(xa.z); a[3] = (short)f2bf(xa.w);
                a[4] = (short)f2bf(xb.x); a[5] = (short)f2bf(xb.y);
                a[6] = (short)f2bf(xb.z); a[7] = (short)f2bf(xb.w);
            } else {
                const unsigned short* X = (const unsigned short*)Xv;
                a = *(const short8*)(X + (size_t)mrc * 128 + kc * 32 + quad * 8);
            }
#pragma unroll
            for (int nt = 0; nt < NT; nt++) {
                short8 b = *(const short8*)(&Wl[(nt * 16 + l16) * 136 + kc * 32 + quad * 8]);
                acc[nt] = __builtin_amdgcn_mfma_f32_16x16x32_bf16(a, b, acc[nt], 0, 0, 0);
            }
        }

        // C layout: col = l16, row (within 16) = quad*4 + i
#pragma unroll
        for (int i = 0; i < 4; i++) {
            int r = m0 + quad * 4 + i;
            if (r >= M) continue;
            float sc = SCALE ? dinv[r] : 1.0f;
#pragma unroll
            for (int nt = 0; nt < NT; nt++) {
                int n = nt * 16 + l16;
                float v = acc[nt][i] * sc;
                if (BIAS) v += bias[n];
                if (OUTF32) {
                    ((float*)outv)[(size_t)r * NOUT + n] = v;
                } else {
                    ((unsigned short*)outv)[(size_t)r * NOUT + n] = f2bf(v);
                }
            }
        }
    }
}

// ---------------- FUSED aggregate + GEMM ----------------
// out = gemm( relu(dinv*(Hs[d] + sum_nbr Hs[src]) + b_agg) , W ), one kernel.
// No global ordering needed across the agg->gemm boundary: each tile's aggregated
// rows depend only on the COMPLETE Hs from the previous launch. Per 64-row tile:
//   phase A: each wave aggregates its 16 rows (2 nodes/wave machinery from the
//            standalone k_aggregate, 8 passes), writes bf16 rows into LDS Xl.
//   phase B: __syncthreads, then the proven k_gemm MFMA body with A from LDS.
// Numerically identical to the unfused chain (same fp32 sums -> same f2bf -> MFMA).
// Saves: 2 launches + the A-buffer round trip (2 x 51 MB store+load).
// shfl discipline: every shfl executes with ALL 64 lanes active; sources stay
// within the issuing 32-lane half (round-1 lesson).

template <int NOUT, bool SCALE, bool BIAS, bool OUTF32>
__global__ __launch_bounds__(256, 3) void k_agg_gemm(
    const unsigned short* __restrict__ Hs, const int* __restrict__ csr,
    const int* __restrict__ row_start, const float* __restrict__ dinv,
    const float* __restrict__ bias_agg, const unsigned short* __restrict__ Wbf,
    const float* __restrict__ bias_out, void* __restrict__ outv,
    int N, int E) {
    __shared__ __align__(16) unsigned short Wl[NOUT * 136];
    __shared__ __align__(16) unsigned short Xl[64 * 136];
    int t = threadIdx.x;
    for (int c = t; c < NOUT * 16; c += 256) {
        short8 v = *(const short8*)(Wbf + (size_t)c * 8);
        *(short8*)(&Wl[(c >> 4) * 136 + (c & 15) * 8]) = v;
    }
    // (no sync yet: Wl and Xl are both read only after the phase-B barrier)

    int wave = t >> 6, lane = t & 63;
    int half = lane >> 5;           // which node of the pair
    int grp = (lane >> 4) & 1;      // edge-slot group within the node
    int c16 = lane & 15;            // channel chunk
    int l32 = lane & 31;            // slot-index space within the node
    int sbase = half << 5;          // shfl source base for this half
    int Nm1 = N - 1;
    unsigned int cb2 = (unsigned int)c16 << 4;
    const char* Hb = (const char*)Hs;

    // agg-epilogue bias depends only on c16: hoist out of the row loop
    float4 bA0 = *(const float4*)(bias_agg + c16 * 8);
    float4 bA1 = *(const float4*)(bias_agg + c16 * 8 + 4);

    // ---- phase A: aggregate this wave's 16 rows, 2 nodes per pass ----
    for (int j = 0; j < 8; ++j) {
        int lr = wave * 16 + 2 * j + half;      // local row in Xl
        int node = blockIdx.x * 64 + lr;        // global node
        int node_c = node < N ? node : Nm1;     // clamp (no early return: shfls)

        int start = row_start[node_c];
        int end = row_start[node_c + 1];
        if (start < 0) start = 0;
        if (end > E) end = E;
        int cnt = end - start;
        if (cnt < 0) cnt = 0;

        // self-loop row: independent load, issued early
        uint4 us = *(const uint4*)(Hb + (((size_t)node_c << 8) | cb2));

        // prefetch up to 32 neighbor indices in one coalesced load, clamp once
        int pre = cnt < 32 ? cnt : 32;
        int idxv = 0;
        if (l32 < pre) idxv = min(max(csr[start + l32], 0), Nm1);

        f32x2 a01 = {0.f, 0.f}, a23 = {0.f, 0.f}, a45 = {0.f, 0.f}, a67 = {0.f, 0.f};
#define ACC8(u) do { a01 += unp2((u).x); a23 += unp2((u).y); \
                     a45 += unp2((u).z); a67 += unp2((u).w); } while (0)
        int full2 = pre >> 1;
        int it = 0;
        for (; it + 4 <= full2; it += 4) {  // sources all within own half
            int p = it * 2 + grp;
            int i0 = __shfl(idxv, sbase + p);
            int i1 = __shfl(idxv, sbase + p + 2);
            int i2 = __shfl(idxv, sbase + p + 4);
            int i3 = __shfl(idxv, sbase + p + 6);
            uint4 u0 = *(const uint4*)(Hb + (((unsigned int)i0 << 8) | cb2));
            uint4 u1 = *(const uint4*)(Hb + (((unsigned int)i1 << 8) | cb2));
            uint4 u2 = *(const uint4*)(Hb + (((unsigned int)i2 << 8) | cb2));
            uint4 u3 = *(const uint4*)(Hb + (((unsigned int)i3 << 8) | cb2));
            ACC8(u0); ACC8(u1); ACC8(u2); ACC8(u3);
        }
        for (; it < full2; it++) {
            int i0 = __shfl(idxv, sbase + it * 2 + grp);
            uint4 u0 = *(const uint4*)(Hb + (((unsigned int)i0 << 8) | cb2));
            ACC8(u0);
        }
        // tail (odd pre): shfl outside the divergent branch, clamped source
        int eT = full2 * 2 + grp;
        int iT = __shfl(idxv, sbase + (eT < pre ? eT : 0));
        if (eT < pre) {
            uint4 u0 = *(const uint4*)(Hb + (((unsigned int)iT << 8) | cb2));
            ACC8(u0);
        }
        // overflow (degree > 32, ~1e-5 of nodes): direct csr loads, no shfl
        for (int e = start + 32 + grp; e < end; e += 2) {
            int ii = min(max(csr[e], 0), Nm1);
            uint4 u = *(const uint4*)(Hb + (((unsigned int)ii << 8) | cb2));
            ACC8(u);
        }
#undef ACC8

        float a0 = a01.x, a1 = a01.y, a2 = a23.x, a3 = a23.y;
        float a4 = a45.x, a5 = a45.y, a6 = a67.x, a7 = a67.y;

        // reduce the 2 edge groups: lanes l <-> l^16 stay within the same half
        a0 += __shfl_xor(a0, 16); a1 += __shfl_xor(a1, 16); a2 += __shfl_xor(a2, 16);
        a3 += __shfl_xor(a3, 16); a4 += __shfl_xor(a4, 16); a5 += __shfl_xor(a5, 16);
        a6 += __shfl_xor(a6, 16); a7 += __shfl_xor(a7, 16);

        // self-loop + agg epilogue; grp 0 of each half writes the bf16 row to LDS
        a0 += bflo(us.x); a1 += bfhi(us.x); a2 += bflo(us.y); a3 += bfhi(us.y);
        a4 += bflo(us.z); a5 += bfhi(us.z); a6 += bflo(us.w); a7 += bfhi(us.w);

        float di = dinv[node_c];
        if (grp == 0) {
            short8 o;
            o[0] = (short)f2bf(fmaxf(fmaf(di, a0, bA0.x), 0.f));
            o[1] = (short)f2bf(fmaxf(fmaf(di, a1, bA0.y), 0.f));
            o[2] = (short)f2bf(fmaxf(fmaf(di, a2, bA0.z), 0.f));
            o[3] = (short)f2bf(fmaxf(fmaf(di, a3, bA0.w), 0.f));
            o[4] = (short)f2bf(fmaxf(fmaf(di, a4, bA1.x), 0.f));
            o[5] = (short)f2bf(fmaxf(fmaf(di, a5, bA1.y), 0.f));
            o[6] = (short)f2bf(fmaxf(fmaf(di, a6, bA1.z), 0.f));
            o[7] = (short)f2bf(fmaxf(fmaf(di, a7, bA1.w), 0.f));
            *(short8*)(&Xl[lr * 136 + c16 * 8]) = o;
        }
    }
    __syncthreads();

    // ---- phase B: MFMA (k_gemm body, A-fragments from LDS Xl) ----
    int quad = lane >> 4, l16 = lane & 15;
    constexpr int NT = NOUT / 16;
    int m0 = blockIdx.x * 64 + wave * 16;

    floatx4 acc[NT];
#pragma unroll
    for (int i = 0; i < NT; i++) acc[i] = (floatx4){0.f, 0.f, 0.f, 0.f};

#pragma unroll
    for (int kc = 0; kc < 4; kc++) {
        short8 a = *(const short8*)(&Xl[(wave * 16 + l16) * 136 + kc * 32 + quad * 8]);
#pragma unroll
        for (int nt = 0; nt < NT; nt++) {
            short8 b = *(const short8*)(&Wl[(nt * 16 + l16) * 136 + kc * 32 + quad * 8]);
            acc[nt] = __builtin_amdgcn_mfma_f32_16x16x32_bf16(a, b, acc[nt], 0, 0, 0);
        }
    }

#pragma unroll
    for (int i = 0; i < 4; i++) {
        int r = m0 + quad * 4 + i;
        if (r >= N) continue;
        float sc = SCALE ? dinv[r] : 1.0f;
#pragma unroll
        for (int nt = 0; nt < NT; nt++) {
            int n = nt * 16 + l16;
            float v = acc[nt][i] * sc;
            if (BIAS) v += bias_out[n];
            if (OUTF32) {
                ((float*)outv)[(size_t)r * NOUT + n] = v;
            } else {
                ((unsigned short*)outv)[(size_t)r * NOUT + n] = f2bf(v);
            }
        }
    }
}

// ---------------- launch ----------------

extern "C" void kernel_launch(void* const* d_in, const int* in_sizes, int n_in,
                              void* d_out, int out_size, void* d_ws, size_t ws_size,
                              hipStream_t stream) {
    const float* x  = (const float*)d_in[0];
    const int* ei   = (const int*)d_in[1];
    const float* W1 = (const float*)d_in[2];
    const float* b1 = (const float*)d_in[3];
    const float* W2 = (const float*)d_in[4];
    const float* b2 = (const float*)d_in[5];
    const float* Wf = (const float*)d_in[6];
    const float* bf = (const float*)d_in[7];

    int N = in_sizes[0] / 128;
    int E = in_sizes[1] / 2;
    const int* src = ei;
    const int* dst = ei + E;
    int K = (N + BK - 1) / BK;
    if (N >= (1 << 24) || K > 512) return;  // packing/scan assumptions

    size_t need = 0;
    auto pad = [](size_t b) { return (b + 255) & ~(size_t)255; };
    size_t o_bcnt = need; need += pad(512 * 4);
    size_t o_boff = need; need += pad(513 * 4);
    size_t o_bcur = need; need += pad(512 * 4);
    size_t o_rs   = need; need += pad(((size_t)N + 1) * 4);
    size_t o_dinv = need; need += pad((size_t)N * 4);
    size_t o_wbf  = need; need += pad((16384 + 16384 + 8192) * 2);
    size_t o_csr  = need; need += pad((size_t)E * 4);
    size_t o_hs   = need; need += pad((size_t)N * 128 * 2);
    size_t o_a    = need; need += pad((size_t)N * 128 * 2);
    if (ws_size < need) return;
    if ((size_t)E * 4 > (size_t)N * 128 * 2) return;  // tmp must fit in Hs2 alias

    char* ws = (char*)d_ws;
    int* bucket_cnt = (int*)(ws + o_bcnt);
    int* bucket_off = (int*)(ws + o_boff);
    int* bucket_cur = (int*)(ws + o_bcur);
    int* row_start  = (int*)(ws + o_rs);
    float* dinv     = (float*)(ws + o_dinv);
    unsigned short* wb1 = (unsigned short*)(ws + o_wbf);
    unsigned short* wb2 = wb1 + 16384;
    unsigned short* wbf = wb2 + 16384;
    int* csr        = (int*)(ws + o_csr);
    unsigned short* Hs  = (unsigned short*)(ws + o_hs);
    unsigned short* Hs2 = (unsigned short*)(ws + o_a);
    unsigned int* tmp   = (unsigned int*)Hs2;  // alias: tmp dead before Hs2's first write

    // ---- CSR build (legacy multi-launch; zero merged into wconv) ----
    k_wconv_all<<<160, 256, 0, stream>>>(W1, W2, Wf, wb1, wb2, wbf, bucket_cnt);
    k_hist<<<256, 256, 0, stream>>>(dst, bucket_cnt, E, N, K);
    k_scanK<<<1, 512, 0, stream>>>(bucket_cnt, bucket_off, bucket_cur, row_start, K, N);
    k_binscatter<<<256, 256, 0, stream>>>(src, dst, bucket_cur, tmp, E, N, K);
    k_fine<<<K, 256, 0, stream>>>(tmp, bucket_off, row_start, dinv, csr, N);

    int MB = (N + 63) / 64;
    int GG = (MB + 1) / 2;  // persistent: 2 row-tiles per block

    // layer 1 dense transform: Hs = dinv * (x @ W1)
    k_gemm<128, true, false, true, false><<<GG, 256, 0, stream>>>(x, wb1, nullptr, dinv, Hs, N, MB);
    // fused agg1 + gemm2: Hs2 = dinv * (relu(dinv*(Hs+sum Hs[src]) + b1) @ W2)
    k_agg_gemm<128, true, false, false><<<MB, 256, 0, stream>>>(
        Hs, csr, row_start, dinv, b1, wb2, nullptr, Hs2, N, E);
    // fused agg2 + gemmf: out = relu(dinv*(Hs2+sum Hs2[src]) + b2) @ Wf + bf
    k_agg_gemm<64, false, true, true><<<MB, 256, 0, stream>>>(
        Hs2, csr, row_start, dinv, b2, wbf, bf, d_out, N, E);
}

// Round 6
// 345.759 us; speedup vs baseline: 1.5038x; 1.0081x over previous
//
#include <hip/hip_runtime.h>
#include <stdint.h>

typedef short short8 __attribute__((ext_vector_type(8)));
typedef float floatx4 __attribute__((ext_vector_type(4)));
typedef float f32x2 __attribute__((ext_vector_type(2)));

#define BK 256   // nodes per bucket

static __device__ __forceinline__ float bflo(unsigned int u) {
    union { unsigned int i; float f; } v; v.i = u << 16; return v.f;
}
static __device__ __forceinline__ float bfhi(unsigned int u) {
    union { unsigned int i; float f; } v; v.i = u & 0xffff0000u; return v.f;
}
static __device__ __forceinline__ unsigned short f2bf(float f) {
    union { float f; unsigned int i; } v; v.f = f;
    unsigned int u = v.i;
    unsigned int r = u + 0x7fffu + ((u >> 16) & 1u);
    return (unsigned short)(r >> 16);
}
// unpack u32 (2 bf16) -> float2 {lo, hi}; feeds v_pk_add_f32
static __device__ __forceinline__ f32x2 unp2(unsigned int u) {
    union { unsigned int i; float f; } lo, hi;
    lo.i = u << 16; hi.i = u & 0xffff0000u;
    f32x2 r; r.x = lo.f; r.y = hi.f; return r;
}

// ---------------- CSR build ----------------
// r4 lesson: grid.sync() costs ~50us/sync on MI355X (cross-XCD) -> multi-launch chain,
// but scanK is merged into hist via the LAST-BLOCK pattern (device-scope atomics only).

// W pre-convert fp32 [K][Nc] -> bf16 transposed [Nc][K]; zeroes bucket_cnt + done flag.
__global__ void k_wconv_all(const float* __restrict__ W1, const float* __restrict__ W2,
                            const float* __restrict__ Wf, unsigned short* __restrict__ wb1,
                            unsigned short* __restrict__ wb2, unsigned short* __restrict__ wbf,
                            int* __restrict__ bucket_cnt, int* __restrict__ done) {
    int i = blockIdx.x * 256 + threadIdx.x;
    if (i == 0) *done = 0;
    if (i < 512) bucket_cnt[i] = 0;
    if (i < 16384) {
        int k = i >> 7, n = i & 127;
        wb1[n * 128 + k] = f2bf(W1[i]);
    } else if (i < 32768) {
        int j = i - 16384, k = j >> 7, n = j & 127;
        wb2[n * 128 + k] = f2bf(W2[j]);
    } else if (i < 40960) {
        int j = i - 32768, k = j >> 6, n = j & 63;
        wbf[n * 128 + k] = f2bf(Wf[j]);
    }
}

// coarse histogram of dst>>8 + LAST-BLOCK exclusive scan (replaces separate k_scanK).
// Producers use device-scope atomicAdd; each thread fences its own atomics, block
// barriers, then one lane bumps the done counter. The block that observes
// done == gridDim-1 reads all 512 counts via atomicAdd(p,0) (RMW at the coherence
// point -> sees all prior atomics) and performs the scan. Entries >= K are zero,
// so bucket_off[K..512] all equal the total, preserving the bucket_off[K] sentinel.
__global__ __launch_bounds__(256) void k_hist_scan(
    const int* __restrict__ dst, int* bucket_cnt, int* bucket_off, int* bucket_cur,
    int* __restrict__ row_start, int* __restrict__ done, int E, int N, int K) {
    __shared__ int h[4][512];
    __shared__ int s[256];
    __shared__ int isLast;
    int t = threadIdx.x, w = t >> 6;
    for (int i = t; i < 4 * 512; i += 256) ((int*)h)[i] = 0;
    __syncthreads();
    int per = (E + gridDim.x - 1) / gridDim.x;
    int lo = blockIdx.x * per, hi = min(lo + per, E);
    for (int e = lo + t; e < hi; e += 256) {
        unsigned int d = (unsigned int)dst[e];
        if (d < (unsigned int)N) atomicAdd(&h[w][d >> 8], 1);
    }
    __syncthreads();
    for (int i = t; i < K; i += 256) {
        int c = h[0][i] + h[1][i] + h[2][i] + h[3][i];
        if (c) atomicAdd(&bucket_cnt[i], c);
    }
    __threadfence();           // this thread's global atomics visible
    __syncthreads();           // whole block fenced
    if (t == 0) isLast = (atomicAdd(done, 1) == (int)gridDim.x - 1);
    __syncthreads();
    if (!isLast) return;
    // scan 512 entries, 2 per thread; atomic reads see all producers' atomics
    int e0 = atomicAdd(&bucket_cnt[2 * t], 0);
    int e1 = atomicAdd(&bucket_cnt[2 * t + 1], 0);
    int p = e0 + e1;
    s[t] = p; __syncthreads();
    for (int off = 1; off < 256; off <<= 1) {
        int x = (t >= off) ? s[t - off] : 0;
        __syncthreads();
        s[t] += x;
        __syncthreads();
    }
    int incl = s[t], excl = incl - p;
    bucket_off[2 * t] = excl;          bucket_cur[2 * t] = excl;
    bucket_off[2 * t + 1] = excl + e0; bucket_cur[2 * t + 1] = excl + e0;
    if (t == 255) { bucket_off[512] = incl; row_start[N] = incl; }
}

// bucket-sort edges into packed 4B entries (src<<8)|(dst&255); per-wave hists/cursors
__global__ __launch_bounds__(256) void k_binscatter(const int* __restrict__ src,
                                                    const int* __restrict__ dst,
                                                    int* bucket_cur, unsigned int* __restrict__ tmp,
                                                    int E, int N, int K) {
    __shared__ int h[4][512];
    int t = threadIdx.x, w = t >> 6;
    for (int i = t; i < 4 * 512; i += 256) ((int*)h)[i] = 0;
    __syncthreads();
    int per = (E + gridDim.x - 1) / gridDim.x;
    int lo = blockIdx.x * per, hi = min(lo + per, E);
    for (int e = lo + t; e < hi; e += 256) {
        unsigned int d = (unsigned int)dst[e];
        if (d < (unsigned int)N) atomicAdd(&h[w][d >> 8], 1);
    }
    __syncthreads();
    for (int k = t; k < K; k += 256) {
        int c0 = h[0][k], c1 = h[1][k], c2 = h[2][k], c3 = h[3][k];
        int tot = c0 + c1 + c2 + c3;
        int base = tot ? atomicAdd(&bucket_cur[k], tot) : 0;
        h[0][k] = base; h[1][k] = base + c0; h[2][k] = base + c0 + c1;
        h[3][k] = base + c0 + c1 + c2;
    }
    __syncthreads();
    for (int e = lo + t; e < hi; e += 256) {
        unsigned int d = (unsigned int)dst[e];
        if (d < (unsigned int)N) {
            unsigned int sv = (unsigned int)src[e];
            if (sv >= (unsigned int)N) sv = 0;
            int p = atomicAdd(&h[w][d >> 8], 1);
            tmp[p] = (sv << 8) | (d & 255u);
        }
    }
}

// one block per bucket: degrees (per-wave hists) -> scan -> dst-sorted csr + dinv
__global__ __launch_bounds__(256) void k_fine(const unsigned int* __restrict__ tmp,
                                              const int* __restrict__ bucket_off,
                                              int* __restrict__ row_start, float* __restrict__ dinv,
                                              int* __restrict__ csr, int N) {
    __shared__ int deg4[4][BK];
    __shared__ int scn[BK];
    __shared__ int cur[BK];
    int b = blockIdx.x, t = threadIdx.x, w = t >> 6;
    int lo = bucket_off[b], hi = bucket_off[b + 1];
    for (int i = t; i < 4 * BK; i += 256) ((int*)deg4)[i] = 0;
    __syncthreads();
    for (int e = lo + t; e < hi; e += 256) atomicAdd(&deg4[w][tmp[e] & 255u], 1);
    __syncthreads();
    int v = deg4[0][t] + deg4[1][t] + deg4[2][t] + deg4[3][t];
    scn[t] = v; __syncthreads();
    for (int off = 1; off < 256; off <<= 1) {
        int x = (t >= off) ? scn[t - off] : 0;
        __syncthreads();
        scn[t] += x;
        __syncthreads();
    }
    int rs = lo + scn[t] - v;
    cur[t] = rs;
    int node = b * BK + t;
    if (node < N) { row_start[node] = rs; dinv[node] = rsqrtf((float)(v + 1)); }
    __syncthreads();
    for (int e = lo + t; e < hi; e += 256) {
        unsigned int p = tmp[e];
        int pos = atomicAdd(&cur[p & 255u], 1);
        csr[pos] = (int)(p >> 8);
    }
}

// ---------------- GEMM (layer 1 only): out[M,128] = X[M,128] @ W[128,128] ----------------

template <int NOUT, bool SCALE, bool BIAS, bool XF32, bool OUTF32>
__global__ __launch_bounds__(256, 2) void k_gemm(
    const void* __restrict__ Xv, const unsigned short* __restrict__ Wbf,
    const float* __restrict__ bias, const float* __restrict__ dinv,
    void* __restrict__ outv, int M, int MB) {
    // Wl[n*136 + k]; stride 136 (272B ≡ 4 banks mod 32 -> 2-way conflict = free)
    __shared__ __align__(16) unsigned short Wl[NOUT * 136];
    int t = threadIdx.x;
    for (int c = t; c < NOUT * 16; c += 256) {
        short8 v = *(const short8*)(Wbf + (size_t)c * 8);
        *(short8*)(&Wl[(c >> 4) * 136 + (c & 15) * 8]) = v;
    }
    __syncthreads();

    int wave = t >> 6, lane = t & 63;
    int quad = lane >> 4, l16 = lane & 15;
    constexpr int NT = NOUT / 16;

    for (int mb = blockIdx.x; mb < MB; mb += gridDim.x) {
        int m0 = mb * 64 + wave * 16;
        int mr = m0 + l16;
        int mrc = mr < M ? mr : M - 1;

        floatx4 acc[NT];
#pragma unroll
        for (int i = 0; i < NT; i++) acc[i] = (floatx4){0.f, 0.f, 0.f, 0.f};

#pragma unroll
        for (int kc = 0; kc < 4; kc++) {
            short8 a;
            if (XF32) {
                const float* X = (const float*)Xv;
                const float* p = X + (size_t)mrc * 128 + kc * 32 + quad * 8;
                float4 xa = *(const float4*)p;
                float4 xb = *(const float4*)(p + 4);
                a[0] = (short)f2bf(xa.x); a[1] = (short)f2bf(xa.y);
                a[2] = (short)f2bf(xa.z); a[3] = (short)f2bf(xa.w);
                a[4] = (short)f2bf(xb.x); a[5] = (short)f2bf(xb.y);
                a[6] = (short)f2bf(xb.z); a[7] = (short)f2bf(xb.w);
            } else {
                const unsigned short* X = (const unsigned short*)Xv;
                a = *(const short8*)(X + (size_t)mrc * 128 + kc * 32 + quad * 8);
            }
#pragma unroll
            for (int nt = 0; nt < NT; nt++) {
                short8 b = *(const short8*)(&Wl[(nt * 16 + l16) * 136 + kc * 32 + quad * 8]);
                acc[nt] = __builtin_amdgcn_mfma_f32_16x16x32_bf16(a, b, acc[nt], 0, 0, 0);
            }
        }

#pragma unroll
        for (int i = 0; i < 4; i++) {
            int r = m0 + quad * 4 + i;
            if (r >= M) continue;
            float sc = SCALE ? dinv[r] : 1.0f;
#pragma unroll
            for (int nt = 0; nt < NT; nt++) {
                int n = nt * 16 + l16;
                float v = acc[nt][i] * sc;
                if (BIAS) v += bias[n];
                if (OUTF32) {
                    ((float*)outv)[(size_t)r * NOUT + n] = v;
                } else {
                    ((unsigned short*)outv)[(size_t)r * NOUT + n] = f2bf(v);
                }
            }
        }
    }
}

// ---------------- FUSED aggregate + GEMM, occupancy-fixed ----------------
// r5 post-mortem: LDS 52KB (3 blk/CU) + VGPR 68 (>64 cliff) starved the gather
// phase (occ 24%, HBM 2.26 TB/s, 96us). Fixes here:
//   * NO W staging in LDS: B-fragments read straight from global (W is 16-32KB,
//     L2-resident on every XCD). LDS = Xl only = 17,408B -> 8 blocks/CU.
//   * phase B processes NOUT in 64-col halves: acc = 4 x floatx4 = 16 VGPR.
//   * __launch_bounds__(256, 8) pins allocator <= 64 VGPR -> 32 waves/CU.
// Phase A is byte-identical to the r3/r5-verified 2-nodes-per-wave aggregate.
// shfl discipline: all shfls execute with all 64 lanes active; sources stay
// within the issuing 32-lane half.

template <int NOUT, bool SCALE, bool BIAS, bool OUTF32>
__global__ __launch_bounds__(256, 8) void k_agg_gemm(
    const unsigned short* __restrict__ Hs, const int* __restrict__ csr,
    const int* __restrict__ row_start, const float* __restrict__ dinv,
    const float* __restrict__ bias_agg, const unsigned short* __restrict__ Wbf,
    const float* __restrict__ bias_out, void* __restrict__ outv,
    int N, int E) {
    __shared__ __align__(16) unsigned short Xl[64 * 136];
    int t = threadIdx.x;
    int wave = t >> 6, lane = t & 63;
    int half = lane >> 5;           // which node of the pair
    int grp = (lane >> 4) & 1;      // edge-slot group within the node
    int c16 = lane & 15;            // channel chunk
    int l32 = lane & 31;            // slot-index space within the node
    int sbase = half << 5;          // shfl source base for this half
    int Nm1 = N - 1;
    unsigned int cb2 = (unsigned int)c16 << 4;
    const char* Hb = (const char*)Hs;

    // agg-epilogue bias depends only on c16: hoist out of the row loop
    float4 bA0 = *(const float4*)(bias_agg + c16 * 8);
    float4 bA1 = *(const float4*)(bias_agg + c16 * 8 + 4);

    // ---- phase A: aggregate this wave's 16 rows, 2 nodes per pass ----
    for (int j = 0; j < 8; ++j) {
        int lr = wave * 16 + 2 * j + half;      // local row in Xl
        int node = blockIdx.x * 64 + lr;        // global node
        int node_c = node < N ? node : Nm1;     // clamp (no early return: shfls)

        int start = row_start[node_c];
        int end = row_start[node_c + 1];
        if (start < 0) start = 0;
        if (end > E) end = E;
        int cnt = end - start;
        if (cnt < 0) cnt = 0;

        // self-loop row: independent load, issued early
        uint4 us = *(const uint4*)(Hb + (((size_t)node_c << 8) | cb2));

        // prefetch up to 32 neighbor indices in one coalesced load, clamp once
        int pre = cnt < 32 ? cnt : 32;
        int idxv = 0;
        if (l32 < pre) idxv = min(max(csr[start + l32], 0), Nm1);

        f32x2 a01 = {0.f, 0.f}, a23 = {0.f, 0.f}, a45 = {0.f, 0.f}, a67 = {0.f, 0.f};
#define ACC8(u) do { a01 += unp2((u).x); a23 += unp2((u).y); \
                     a45 += unp2((u).z); a67 += unp2((u).w); } while (0)
        int full2 = pre >> 1;
        int it = 0;
        for (; it + 4 <= full2; it += 4) {  // sources all within own half
            int p = it * 2 + grp;
            int i0 = __shfl(idxv, sbase + p);
            int i1 = __shfl(idxv, sbase + p + 2);
            int i2 = __shfl(idxv, sbase + p + 4);
            int i3 = __shfl(idxv, sbase + p + 6);
            uint4 u0 = *(const uint4*)(Hb + (((unsigned int)i0 << 8) | cb2));
            uint4 u1 = *(const uint4*)(Hb + (((unsigned int)i1 << 8) | cb2));
            uint4 u2 = *(const uint4*)(Hb + (((unsigned int)i2 << 8) | cb2));
            uint4 u3 = *(const uint4*)(Hb + (((unsigned int)i3 << 8) | cb2));
            ACC8(u0); ACC8(u1); ACC8(u2); ACC8(u3);
        }
        for (; it < full2; it++) {
            int i0 = __shfl(idxv, sbase + it * 2 + grp);
            uint4 u0 = *(const uint4*)(Hb + (((unsigned int)i0 << 8) | cb2));
            ACC8(u0);
        }
        // tail (odd pre): shfl outside the divergent branch, clamped source
        int eT = full2 * 2 + grp;
        int iT = __shfl(idxv, sbase + (eT < pre ? eT : 0));
        if (eT < pre) {
            uint4 u0 = *(const uint4*)(Hb + (((unsigned int)iT << 8) | cb2));
            ACC8(u0);
        }
        // overflow (degree > 32, ~1e-5 of nodes): direct csr loads, no shfl
        for (int e = start + 32 + grp; e < end; e += 2) {
            int ii = min(max(csr[e], 0), Nm1);
            uint4 u = *(const uint4*)(Hb + (((unsigned int)ii << 8) | cb2));
            ACC8(u);
        }
#undef ACC8

        float a0 = a01.x, a1 = a01.y, a2 = a23.x, a3 = a23.y;
        float a4 = a45.x, a5 = a45.y, a6 = a67.x, a7 = a67.y;

        // reduce the 2 edge groups: lanes l <-> l^16 stay within the same half
        a0 += __shfl_xor(a0, 16); a1 += __shfl_xor(a1, 16); a2 += __shfl_xor(a2, 16);
        a3 += __shfl_xor(a3, 16); a4 += __shfl_xor(a4, 16); a5 += __shfl_xor(a5, 16);
        a6 += __shfl_xor(a6, 16); a7 += __shfl_xor(a7, 16);

        // self-loop + agg epilogue; grp 0 of each half writes the bf16 row to LDS
        a0 += bflo(us.x); a1 += bfhi(us.x); a2 += bflo(us.y); a3 += bfhi(us.y);
        a4 += bflo(us.z); a5 += bfhi(us.z); a6 += bflo(us.w); a7 += bfhi(us.w);

        float di = dinv[node_c];
        if (grp == 0) {
            short8 o;
            o[0] = (short)f2bf(fmaxf(fmaf(di, a0, bA0.x), 0.f));
            o[1] = (short)f2bf(fmaxf(fmaf(di, a1, bA0.y), 0.f));
            o[2] = (short)f2bf(fmaxf(fmaf(di, a2, bA0.z), 0.f));
            o[3] = (short)f2bf(fmaxf(fmaf(di, a3, bA0.w), 0.f));
            o[4] = (short)f2bf(fmaxf(fmaf(di, a4, bA1.x), 0.f));
            o[5] = (short)f2bf(fmaxf(fmaf(di, a5, bA1.y), 0.f));
            o[6] = (short)f2bf(fmaxf(fmaf(di, a6, bA1.z), 0.f));
            o[7] = (short)f2bf(fmaxf(fmaf(di, a7, bA1.w), 0.f));
            *(short8*)(&Xl[lr * 136 + c16 * 8]) = o;
        }
    }
    __syncthreads();

    // ---- phase B: MFMA over NOUT in 64-col halves; B-fragments from global ----
    int quad = lane >> 4, l16 = lane & 15;
    constexpr int NH = NOUT / 64;   // 2 for NOUT=128, 1 for NOUT=64
    int m0 = blockIdx.x * 64 + wave * 16;

#pragma unroll
    for (int hh = 0; hh < NH; hh++) {
        floatx4 acc[4];
#pragma unroll
        for (int i = 0; i < 4; i++) acc[i] = (floatx4){0.f, 0.f, 0.f, 0.f};

#pragma unroll
        for (int kc = 0; kc < 4; kc++) {
            short8 a = *(const short8*)(&Xl[(wave * 16 + l16) * 136 + kc * 32 + quad * 8]);
#pragma unroll
            for (int nt = 0; nt < 4; nt++) {
                int n = hh * 64 + nt * 16 + l16;
                short8 b = *(const short8*)(Wbf + (size_t)n * 128 + kc * 32 + quad * 8);
                acc[nt] = __builtin_amdgcn_mfma_f32_16x16x32_bf16(a, b, acc[nt], 0, 0, 0);
            }
        }

#pragma unroll
        for (int i = 0; i < 4; i++) {
            int r = m0 + quad * 4 + i;
            if (r >= N) continue;
            float sc = SCALE ? dinv[r] : 1.0f;
#pragma unroll
            for (int nt = 0; nt < 4; nt++) {
                int n = hh * 64 + nt * 16 + l16;
                float v = acc[nt][i] * sc;
                if (BIAS) v += bias_out[n];
                if (OUTF32) {
                    ((float*)outv)[(size_t)r * NOUT + n] = v;
                } else {
                    ((unsigned short*)outv)[(size_t)r * NOUT + n] = f2bf(v);
                }
            }
        }
    }
}

// ---------------- launch ----------------

extern "C" void kernel_launch(void* const* d_in, const int* in_sizes, int n_in,
                              void* d_out, int out_size, void* d_ws, size_t ws_size,
                              hipStream_t stream) {
    const float* x  = (const float*)d_in[0];
    const int* ei   = (const int*)d_in[1];
    const float* W1 = (const float*)d_in[2];
    const float* b1 = (const float*)d_in[3];
    const float* W2 = (const float*)d_in[4];
    const float* b2 = (const float*)d_in[5];
    const float* Wf = (const float*)d_in[6];
    const float* bf = (const float*)d_in[7];

    int N = in_sizes[0] / 128;
    int E = in_sizes[1] / 2;
    const int* src = ei;
    const int* dst = ei + E;
    int K = (N + BK - 1) / BK;
    if (N >= (1 << 24) || K > 512) return;  // packing/scan assumptions

    size_t need = 0;
    auto pad = [](size_t b) { return (b + 255) & ~(size_t)255; };
    size_t o_bcnt = need; need += pad(512 * 4);
    size_t o_boff = need; need += pad(513 * 4);
    size_t o_bcur = need; need += pad(512 * 4);
    size_t o_flag = need; need += pad(4);
    size_t o_rs   = need; need += pad(((size_t)N + 1) * 4);
    size_t o_dinv = need; need += pad((size_t)N * 4);
    size_t o_wbf  = need; need += pad((16384 + 16384 + 8192) * 2);
    size_t o_csr  = need; need += pad((size_t)E * 4);
    size_t o_hs   = need; need += pad((size_t)N * 128 * 2);
    size_t o_a    = need; need += pad((size_t)N * 128 * 2);
    if (ws_size < need) return;
    if ((size_t)E * 4 > (size_t)N * 128 * 2) return;  // tmp must fit in Hs2 alias

    char* ws = (char*)d_ws;
    int* bucket_cnt = (int*)(ws + o_bcnt);
    int* bucket_off = (int*)(ws + o_boff);
    int* bucket_cur = (int*)(ws + o_bcur);
    int* done       = (int*)(ws + o_flag);
    int* row_start  = (int*)(ws + o_rs);
    float* dinv     = (float*)(ws + o_dinv);
    unsigned short* wb1 = (unsigned short*)(ws + o_wbf);
    unsigned short* wb2 = wb1 + 16384;
    unsigned short* wbf = wb2 + 16384;
    int* csr        = (int*)(ws + o_csr);
    unsigned short* Hs  = (unsigned short*)(ws + o_hs);
    unsigned short* Hs2 = (unsigned short*)(ws + o_a);
    unsigned int* tmp   = (unsigned int*)Hs2;  // alias: tmp dead before Hs2's first write

    // ---- CSR build: 4 launches (zero+wconv merged; scanK merged into hist) ----
    k_wconv_all<<<160, 256, 0, stream>>>(W1, W2, Wf, wb1, wb2, wbf, bucket_cnt, done);
    k_hist_scan<<<256, 256, 0, stream>>>(dst, bucket_cnt, bucket_off, bucket_cur,
                                         row_start, done, E, N, K);
    k_binscatter<<<256, 256, 0, stream>>>(src, dst, bucket_cur, tmp, E, N, K);
    k_fine<<<K, 256, 0, stream>>>(tmp, bucket_off, row_start, dinv, csr, N);

    int MB = (N + 63) / 64;
    int GG = (MB + 1) / 2;  // persistent: 2 row-tiles per block

    // layer 1 dense transform: Hs = dinv * (x @ W1)
    k_gemm<128, true, false, true, false><<<GG, 256, 0, stream>>>(x, wb1, nullptr, dinv, Hs, N, MB);
    // fused agg1 + gemm2: Hs2 = dinv * (relu(dinv*(Hs+sum Hs[src]) + b1) @ W2)
    k_agg_gemm<128, true, false, false><<<MB, 256, 0, stream>>>(
        Hs, csr, row_start, dinv, b1, wb2, nullptr, Hs2, N, E);
    // fused agg2 + gemmf: out = relu(dinv*(Hs2+sum Hs2[src]) + b2) @ Wf + bf
    k_agg_gemm<64, false, true, true><<<MB, 256, 0, stream>>>(
        Hs2, csr, row_start, dinv, b2, wbf, bf, d_out, N, E);
}